// Round 6
// baseline (296.420 us; speedup 1.0000x reference)
//
#include <hip/hip_runtime.h>
#include <hip/hip_bf16.h>

typedef unsigned short u16;
typedef __bf16 bf16x8 __attribute__((ext_vector_type(8)));
typedef float floatx4 __attribute__((ext_vector_type(4)));
typedef __hip_bfloat16 bf;

__device__ __forceinline__ __bf16 f2b(float f) {
    __hip_bfloat16 h = __float2bfloat16(f);
    return *reinterpret_cast<__bf16*>(&h);
}
__device__ __forceinline__ bf16x8 ld8f(const float* p) {
    float4 a = ((const float4*)p)[0];
    float4 b = ((const float4*)p)[1];
    bf16x8 r;
    r[0] = f2b(a.x); r[1] = f2b(a.y); r[2] = f2b(a.z); r[3] = f2b(a.w);
    r[4] = f2b(b.x); r[5] = f2b(b.y); r[6] = f2b(b.z); r[7] = f2b(b.w);
    return r;
}
__device__ __forceinline__ void storev(float* p, float v) { *p = v; }
__device__ __forceinline__ void storev(bf* p, float v)    { *p = __float2bfloat16(v); }

// async 16-B global->LDS (used only by gemm128 this round)
__device__ __forceinline__ void gl16(const bf* g, u16* l) {
    __builtin_amdgcn_global_load_lds(
        (const __attribute__((address_space(1))) void*)g,
        (__attribute__((address_space(3))) void*)l, 16, 0, 0);
}

// T1 bijective XCD swizzle (all our grids have nwg % 8 == 0)
__device__ __forceinline__ void swz3(int& bx, int& by, int& bz) {
    const int nx = gridDim.x, ny = gridDim.y, nz = gridDim.z;
    const int lid = blockIdx.x + nx * (blockIdx.y + ny * blockIdx.z);
    const int cpx = (nx * ny * nz) >> 3;
    const int s = (lid & 7) * cpx + (lid >> 3);
    bx = s % nx;
    const int r = s / nx;
    by = r % ny;
    bz = r / ny;
}

#define FENCE asm volatile("" ::: "memory")
#define BARx  __builtin_amdgcn_s_barrier()
#define LGKM0 asm volatile("s_waitcnt lgkmcnt(0)" ::: "memory")
#define VM3   asm volatile("s_waitcnt vmcnt(3)" ::: "memory")
#define VM0   asm volatile("s_waitcnt vmcnt(0)" ::: "memory")
#define SP1   __builtin_amdgcn_s_setprio(1)
#define SP0   __builtin_amdgcn_s_setprio(0)

// ============================================================================
// Kernel A (R6): 256x256-tile 8-phase NT GEMM, REG-STAGED (T14).
// R2-R5 plateau (26-28% MfmaUtil across 3 barrier variants) diagnosed as the
// LDS-DMA hazard: hipcc's waitcnt legalizer conservatively vmcnt-drains before
// ds_reads that may alias outstanding global_load_lds -> full drain per phase,
// pipeline collapsed.  Fix per the T-catalog dep graph: reg-stage
// (global_load_dwordx4 -> reg -> ds_write_b128).  All waits become precise
// compiler-counted reg-dependency waits; NO explicit vmcnt at all.
//
// Geometry: BK=64, 512 thr, 8 waves 2Mx4N, per-wave 128x64, acc[8][4] (AGPR).
// LDS 128 KiB: buf0{A0b,B0b} buf1{A1b,B1b}, each [256][64], unit = 64 rows.
// Operands: a[8] + single b[4] (B0 re-read at ph4; +4 reads/K-tile buys
// -16 VGPR so staging regs fit the 256/wave unified budget).
//
// Per phase: {ds_reads | WR: ds_write unit loaded 2 phases ago | LD: issue
// 2 global_load_dwordx4 for unit due 2 phases ahead | MFMA | lgkm0 | BAR}.
// Write slots (unit-by-unit staircase, all gaps >= 1 barrier):
//   ph1: B1b.u0,u1 (t+1)  [skip it=0]   ph5: B0b.u0,u1 (t+2)
//   ph2: B1b.u2,u3 (t+1)  [skip it=0]   ph6: B0b.u2,u3 (t+2)
//   ph3: A0b.u0,u2 (t+2)                ph7: A1b.u0,u2 (t+3)
//   ph4: A0b.u1,u3 (t+2)                ph8: A1b.u1,u3 (t+3)
// Issue slots = write slot - 2 phases (ph7/ph8 feed next iter's ph1/ph2 via
// loop-carried reg sets pA,pB / qA,qB).  Clobber/first-read checks:
//   writes vs last read: B1b@ph1<-prev ph8 re-read ok(1); A0b.u0,u2@ph3<-ph1(2);
//   A0b.u1,u3@ph4<-ph3(1); B0b@ph5,6<-ph4 re-read(1,2); A1b@ph7,8<-ph5,ph7(2,1).
//   first reads: B1b t+1 @ph5 (w ph1,2); A0b/B0b t+2 @next ph1 (w ph3..6);
//   A1b t+3 @next ph5 (w ph7,8).  All separated by >= 1 barrier + writer lgkm0.
// LDS k-swizzle unchanged (R2: SQ_LDS_BANK_CONFLICT = 0).  K % 128 == 0.
// ============================================================================

#define RD_A2(dst, h, Ab) do { _Pragma("unroll") \
    for (int q_ = 0; q_ < 4; q_++) { \
        const u16* p_ = (Ab) + (wg * 128 + (h) * 64 + q_ * 16 + fr) * 64; \
        dst[q_ * 2 + 0] = *(const bf16x8*)(p_ + kl0); \
        dst[q_ * 2 + 1] = *(const bf16x8*)(p_ + kl1); \
    } } while (0)

#define RD_B2(dst, c, Bb) do { _Pragma("unroll") \
    for (int j_ = 0; j_ < 2; j_++) { \
        const u16* p_ = (Bb) + (w4 * 64 + (c) * 32 + j_ * 16 + fr) * 64; \
        dst[j_ * 2 + 0] = *(const bf16x8*)(p_ + kl0); \
        dst[j_ * 2 + 1] = *(const bf16x8*)(p_ + kl1); \
    } } while (0)

#define QMM2(h, c, av, bv) do { _Pragma("unroll") \
    for (int q_ = 0; q_ < 4; q_++) _Pragma("unroll") \
    for (int j_ = 0; j_ < 2; j_++) _Pragma("unroll") \
    for (int kk_ = 0; kk_ < 2; kk_++) \
        acc[(h) * 4 + q_][(c) * 2 + j_] = __builtin_amdgcn_mfma_f32_16x16x32_bf16( \
            av[q_ * 2 + kk_], bv[j_ * 2 + kk_], acc[(h) * 4 + q_][(c) * 2 + j_], 0, 0, 0); \
} while (0)

#define LD_AU(r, u, kt) (r) = *(const uint4*)(Asrc + (long)((u) * 64) * K + (long)(kt) * 64)
#define LD_BU(r, u, kt) (r) = *(const uint4*)(Bsrc + (long)((u) * 64) * K + (long)(kt) * 64)
#define WRU(buf, u, r)  *(uint4*)((buf) + (u) * 4096 + tid * 8) = (r)

template <typename OutT>
__device__ __forceinline__ void gemm256_core(
    const bf* __restrict__ A, const bf* __restrict__ B, OutT* __restrict__ C,
    int K, int N, int m_blk, int n_blk, float scale, u16* lds)
{
    const int tid = threadIdx.x;
    const int w = tid >> 6, lane = tid & 63;
    const int wg = w >> 2, w4 = w & 3;          // wave grid 2M x 4N
    const int fr = lane & 15, kg = lane >> 4;

    u16* const A0b = lds;                        // [256][64]
    u16* const B0b = lds + 16384;
    u16* const A1b = lds + 32768;
    u16* const B1b = lds + 49152;                // 65536 elems = 128 KiB

    const int kl0 = (kg * 8) ^ ((fr & 7) << 3);
    const int kl1 = kl0 ^ 32;

    // staging: thread covers LDS row sr (of a 64-row unit), 16B chunk tid&7;
    // source col pre-swizzled so linear LDS + swizzled read are consistent
    const int sr  = tid >> 3;                    // 0..63
    const int scs = ((tid & 7) * 8) ^ ((sr & 7) << 3);
    const bf* Asrc = A + (long)(m_blk + sr) * K + scs;
    const bf* Bsrc = B + (long)(n_blk + sr) * K + scs;

    floatx4 acc[8][4];
#pragma unroll
    for (int i = 0; i < 8; i++)
#pragma unroll
        for (int j = 0; j < 4; j++) acc[i][j] = (floatx4){0.f, 0.f, 0.f, 0.f};

    bf16x8 a[8], b[4];
    uint4 pA, pB, qA, qB;                        // loop-carried staging sets

    const int T     = K >> 6;    // K-tiles, even
    const int iters = T >> 1;

    // prologue: reg-stage tiles 0 -> buf0, 1 -> buf1
#pragma unroll
    for (int u = 0; u < 4; u++) {
        uint4 ra, rb; LD_AU(ra, u, 0); LD_BU(rb, u, 0);
        WRU(A0b, u, ra); WRU(B0b, u, rb);
    }
#pragma unroll
    for (int u = 0; u < 4; u++) {
        uint4 ra, rb; LD_AU(ra, u, 1); LD_BU(rb, u, 1);
        WRU(A1b, u, ra); WRU(B1b, u, rb);
    }
    LGKM0; BARx; FENCE;

    for (int it = 0; it < iters; ++it) {
        const int t   = it * 2;
        const int ts0 = (t + 2 < T) ? t + 2 : 0;   // clamped: garbage unused
        const int ts1 = (t + 3 < T) ? t + 3 : 0;

        // ph1: Q(A0,B0c0)
        RD_A2(a, 0, A0b); RD_B2(b, 0, B0b);
        if (it) { WRU(B1b, 0, pA); WRU(B1b, 1, pB); }     // t+1 B (iss prev ph7)
        LD_AU(pA, 0, ts0); LD_AU(pB, 2, ts0);             // -> ph3
        SP1; QMM2(0, 0, a, b); SP0; LGKM0; BARx; FENCE;

        // ph2: Q(A0,B0c1)
        RD_B2(b, 1, B0b);
        if (it) { WRU(B1b, 2, qA); WRU(B1b, 3, qB); }     // t+1 B (iss prev ph8)
        LD_AU(qA, 1, ts0); LD_AU(qB, 3, ts0);             // -> ph4
        SP1; QMM2(0, 1, a, b); SP0; LGKM0; BARx; FENCE;

        // ph3: Q(A1,B0c1)
        RD_A2(a, 1, A0b);
        WRU(A0b, 0, pA); WRU(A0b, 2, pB);                 // t+2 A even units
        LD_BU(pA, 0, ts0); LD_BU(pB, 1, ts0);             // -> ph5
        SP1; QMM2(1, 1, a, b); SP0; LGKM0; BARx; FENCE;

        // ph4: Q(A1,B0c0) — re-read c0
        RD_B2(b, 0, B0b);
        WRU(A0b, 1, qA); WRU(A0b, 3, qB);                 // t+2 A odd units
        LD_BU(qA, 2, ts0); LD_BU(qB, 3, ts0);             // -> ph6
        SP1; QMM2(1, 0, a, b); SP0; LGKM0; BARx; FENCE;

        // ph5
        RD_A2(a, 0, A1b); RD_B2(b, 0, B1b);
        WRU(B0b, 0, pA); WRU(B0b, 1, pB);                 // t+2 B
        LD_AU(pA, 0, ts1); LD_AU(pB, 2, ts1);             // -> ph7
        SP1; QMM2(0, 0, a, b); SP0; LGKM0; BARx; FENCE;

        // ph6
        RD_B2(b, 1, B1b);
        WRU(B0b, 2, qA); WRU(B0b, 3, qB);                 // t+2 B
        LD_AU(qA, 1, ts1); LD_AU(qB, 3, ts1);             // -> ph8
        SP1; QMM2(0, 1, a, b); SP0; LGKM0; BARx; FENCE;

        // ph7
        RD_A2(a, 1, A1b);
        WRU(A1b, 0, pA); WRU(A1b, 2, pB);                 // t+3 A even
        LD_BU(pA, 0, ts1); LD_BU(pB, 1, ts1);             // -> next ph1
        SP1; QMM2(1, 1, a, b); SP0; LGKM0; BARx; FENCE;

        // ph8 — re-read c0
        RD_B2(b, 0, B1b);
        WRU(A1b, 1, qA); WRU(A1b, 3, qB);                 // t+3 A odd
        LD_BU(qA, 2, ts1); LD_BU(qB, 3, ts1);             // -> next ph2
        SP1; QMM2(1, 0, a, b); SP0; LGKM0; BARx; FENCE;
    }

    // C-write: col=lane&15, row=(lane>>4)*4+reg  [m89/m91]
    const long c_col0 = n_blk + w4 * 64 + fr;
    const long c_row0 = m_blk + wg * 128 + (lane >> 4) * 4;
#pragma unroll
    for (int rf = 0; rf < 8; rf++)
#pragma unroll
        for (int r = 0; r < 4; r++) {
            const long row = c_row0 + rf * 16 + r;
#pragma unroll
            for (int cf = 0; cf < 4; cf++)
                storev(&C[row * N + c_col0 + cf * 16], acc[rf][cf][r] * scale);
        }
}

template <typename OutT>
__global__ __launch_bounds__(512)
void gemm256(const bf* __restrict__ A, const bf* __restrict__ B,
             OutT* __restrict__ C, int K, int N,
             long sA, long sB, long sC, float scale)
{
    __shared__ __align__(16) u16 lds[65536];   // 128 KiB
    int bx, by, bz; swz3(bx, by, bz);
    gemm256_core(A + bz * sA, B + bz * sB, C + bz * sC,
                 K, N, by * 256, bx * 256, scale, lds);
}

__global__ __launch_bounds__(512)
void gemm256_qk(const bf* __restrict__ xb, const bf* __restrict__ memb,
                const bf* __restrict__ Wqb, const bf* __restrict__ Wkb,
                bf* __restrict__ Q, bf* __restrict__ Kp, float qscale)
{
    __shared__ __align__(16) u16 lds[65536];
    int bx, by, bz; swz3(bx, by, bz);
    gemm256_core(bz ? memb : xb, bz ? Wkb : Wqb, bz ? Kp : Q, 1024, 1024,
                 by * 256, bx * 256, bz ? 1.f : qscale, lds);
}

// ---------------- Kernel B: 128x256 tile, 4-phase, gl16 (unchanged R5) -----

#define ST_A(h, kt, Ab) \
    gl16(Asrc + (long)((h) * 32) * K + (long)(kt) * 64, (Ab) + (h) * 4096 + tid * 8)
#define ST_Bu0(c, kt, Bb) \
    gl16(Bsrc + (long)((c) * 32) * K + (long)(kt) * 64, (Bb) + (c) * 8192 + tid * 8)
#define ST_Bu1(c, kt, Bb) \
    gl16(Bsrc + (long)((c) * 32 + 128) * K + (long)(kt) * 64, (Bb) + (c) * 8192 + 4096 + tid * 8)

#define RD_A(dst, h, Ab) do { _Pragma("unroll") \
    for (int q_ = 0; q_ < 2; q_++) { \
        const u16* p_ = (Ab) + ((h) * 64 + wg * 32 + q_ * 16 + fr) * 64; \
        dst[q_ * 2 + 0] = *(const bf16x8*)(p_ + kl0); \
        dst[q_ * 2 + 1] = *(const bf16x8*)(p_ + kl1); \
    } } while (0)

#define RD_B(dst, c, Bb) do { _Pragma("unroll") \
    for (int j_ = 0; j_ < 2; j_++) { \
        const u16* p_ = (Bb) + ((c) * 128 + w4 * 32 + j_ * 16 + fr) * 64; \
        dst[j_ * 2 + 0] = *(const bf16x8*)(p_ + kl0); \
        dst[j_ * 2 + 1] = *(const bf16x8*)(p_ + kl1); \
    } } while (0)

#define QMM(h, c, av, bv) do { _Pragma("unroll") \
    for (int q_ = 0; q_ < 2; q_++) _Pragma("unroll") \
    for (int j_ = 0; j_ < 2; j_++) _Pragma("unroll") \
    for (int kk_ = 0; kk_ < 2; kk_++) \
        acc[(h) * 2 + q_][(c) * 2 + j_] = __builtin_amdgcn_mfma_f32_16x16x32_bf16( \
            av[q_ * 2 + kk_], bv[j_ * 2 + kk_], acc[(h) * 2 + q_][(c) * 2 + j_], 0, 0, 0); \
} while (0)

template <typename OutT>
__device__ __forceinline__ void gemm128_core(
    const bf* __restrict__ A, const bf* __restrict__ B, OutT* __restrict__ C,
    int K, int N, int m_blk, int n_blk, float scale, u16* lds)
{
    const int tid  = threadIdx.x;
    const int w    = tid >> 6, lane = tid & 63;
    const int wg   = w >> 2, w4 = w & 3;
    const int fr   = lane & 15, kg = lane >> 4;

    u16* const A0b = lds;
    u16* const B0b = lds + 8192;
    u16* const A1b = lds + 24576;
    u16* const B1b = lds + 32768;

    const int kl0 = (kg * 8) ^ ((fr & 7) << 3);
    const int kl1 = kl0 ^ 32;

    const int sr  = tid >> 3;
    const int scs = ((tid & 7) * 8) ^ ((sr & 7) << 3);
    const bf* Asrc = A + (long)(m_blk + (tid >> 8) * 64 + (sr & 31)) * K + scs;
    const bf* Bsrc = B + (long)(n_blk + (tid >> 8) * 64 + (sr & 31)) * K + scs;

    floatx4 acc[4][4];
#pragma unroll
    for (int i = 0; i < 4; i++)
#pragma unroll
        for (int j = 0; j < 4; j++) acc[i][j] = (floatx4){0.f, 0.f, 0.f, 0.f};

    bf16x8 a0[4], a1[4], b0[4], b1[4];

    const int T     = K >> 6;
    const int iters = T >> 1;

    ST_A(0, 0, A0b); ST_A(1, 0, A0b);
    ST_Bu0(0, 0, B0b); ST_Bu1(0, 0, B0b); ST_Bu0(1, 0, B0b); ST_Bu1(1, 0, B0b);
    ST_A(0, 1, A1b); ST_A(1, 1, A1b);
    ST_Bu0(0, 1, B1b); ST_Bu1(0, 1, B1b); ST_Bu0(1, 1, B1b); ST_Bu1(1, 1, B1b);
    VM0; BARx; FENCE;

    for (int it = 0; it < iters; ++it) {
        const int t   = it * 2;
        const int ts0 = (t + 2 < T) ? t + 2 : 0;
        const int ts1 = (t + 3 < T) ? t + 3 : 0;

        RD_A(a0, 0, A0b); RD_A(a1, 1, A0b); RD_B(b0, 0, B0b);
        if (it) { ST_Bu1(0, t + 1, B1b); ST_Bu0(1, t + 1, B1b); ST_Bu1(1, t + 1, B1b); }
        SP1; QMM(0, 0, a0, b0); QMM(1, 0, a1, b0); SP0;
        FENCE; BARx; FENCE;

        RD_B(b1, 1, B0b);
        ST_A(0, ts0, A0b); ST_A(1, ts0, A0b); ST_Bu0(0, ts0, B0b);
        SP1; QMM(0, 1, a0, b1); QMM(1, 1, a1, b1); SP0;
        VM3; BARx; FENCE;

        RD_A(a0, 0, A1b); RD_A(a1, 1, A1b); RD_B(b0, 0, B1b);
        ST_Bu1(0, ts0, B0b); ST_Bu0(1, ts0, B0b); ST_Bu1(1, ts0, B0b);
        SP1; QMM(0, 0, a0, b0); QMM(1, 0, a1, b0); SP0;
        FENCE; BARx; FENCE;

        RD_B(b1, 1, B1b);
        ST_A(0, ts1, A1b); ST_A(1, ts1, A1b); ST_Bu0(0, ts1, B1b);
        SP1; QMM(0, 1, a0, b1); QMM(1, 1, a1, b1); SP0;
        VM3; BARx; FENCE;
    }

    const long c_col0 = n_blk + w4 * 64 + fr;
    const long c_row0 = m_blk + wg * 64 + (lane >> 4) * 4;
#pragma unroll
    for (int rf = 0; rf < 4; rf++)
#pragma unroll
        for (int r = 0; r < 4; r++) {
            const long row = c_row0 + rf * 16 + r;
#pragma unroll
            for (int cf = 0; cf < 4; cf++)
                storev(&C[row * N + c_col0 + cf * 16], acc[rf][cf][r] * scale);
        }
}

template <typename OutT>
__global__ __launch_bounds__(512)
void gemm128(const bf* __restrict__ A, const bf* __restrict__ B,
             OutT* __restrict__ C, int K, int N,
             long sA, long sB, long sC, float scale)
{
    __shared__ __align__(16) u16 lds[49152];   // 96 KiB
    int bx, by, bz; swz3(bx, by, bz);
    gemm128_core(A + bz * sA, B + bz * sB, C + bz * sC,
                 K, N, by * 128, bx * 256, scale, lds);
}

// ============================================================================
// fp32 -> bf16 conversion pre-pass
// ============================================================================
__global__ __launch_bounds__(256)
void cvt2(const float* __restrict__ a, const float* __restrict__ b,
          bf* __restrict__ da, bf* __restrict__ db, long n)
{
    const float* s = blockIdx.z ? b : a;
    bf* d = blockIdx.z ? db : da;
    const long stride = (long)gridDim.x * 256;
    for (long i = (long)blockIdx.x * 256 + threadIdx.x; i * 8 < n; i += stride)
        *(bf16x8*)(d + i * 8) = ld8f(s + i * 8);
}

__global__ __launch_bounds__(256)
void cvt_w(const float* __restrict__ w0, const float* __restrict__ w1,
           const float* __restrict__ w2, const float* __restrict__ w3,
           bf* __restrict__ d)
{
    const int z = blockIdx.z;
    const float* s = (z == 0) ? w0 : (z == 1) ? w1 : (z == 2) ? w2 : w3;
    bf* dz = d + (long)z * (1 << 20);
    const long i = ((long)blockIdx.x * 256 + threadIdx.x) * 8;
    *(bf16x8*)(dz + i) = ld8f(s + i);
}

// ============================================================================
// In-place bf16 row softmax over 2048 logits; one block per row.
// ============================================================================
__global__ __launch_bounds__(256)
void softmax_rows_2048(bf* __restrict__ X)
{
    const long row = blockIdx.x;
    const int t = threadIdx.x;
    const int wave = t >> 6, lane = t & 63;
    __shared__ float red[8];

    float v[8];
    float m = -1e30f;
#pragma unroll
    for (int i = 0; i < 8; i++) {
        v[i] = __bfloat162float(X[row * 2048 + t + i * 256]);
        m = fmaxf(m, v[i]);
    }
#pragma unroll
    for (int o = 32; o > 0; o >>= 1) m = fmaxf(m, __shfl_xor(m, o, 64));
    if (lane == 0) red[wave] = m;
    __syncthreads();
    m = fmaxf(fmaxf(red[0], red[1]), fmaxf(red[2], red[3]));

    float s = 0.f;
#pragma unroll
    for (int i = 0; i < 8; i++) { v[i] = __expf(v[i] - m); s += v[i]; }
#pragma unroll
    for (int o = 32; o > 0; o >>= 1) s += __shfl_xor(s, o, 64);
    if (lane == 0) red[4 + wave] = s;
    __syncthreads();
    s = red[4] + red[5] + red[6] + red[7];

    const float inv = 1.f / s;
#pragma unroll
    for (int i = 0; i < 8; i++)
        X[row * 2048 + t + i * 256] = __float2bfloat16(v[i] * inv);
}

// ============================================================================
// Pipeline (8 dispatches):
//   1. cvt2   x,mem -> xb,memb bf16 (in d_out, dead after logits)
//   2. cvt_w  weights -> bf16 (ws chunk 3)
//   3. qk     gemm256(reg-staged) grid(4,32,2)=256   M=8192,N=1024,K=1024
//   4. Vt     gemm128 grid(8,8,4)=256                M=1024,N=2048,K=1024
//   5. logits gemm256(reg-staged) grid(8,8,4)=256    M=N=2048,K=1024
//   6. softmax 8192 blk in place
//   7. AO     gemm128 grid(4,16,4)=256               M=2048,N=1024,K=2048
//   8. final  gemm128 grid(4,64,1)=256               M=8192,N=1024,K=1024
// Workspace: Q/AO 16 + Kp 16 + Vt 16 + Wb 8 = 56 MiB.
// ============================================================================
extern "C" void kernel_launch(void* const* d_in, const int* in_sizes, int n_in,
                              void* d_out, int out_size, void* d_ws, size_t ws_size,
                              hipStream_t stream)
{
    const float* x   = (const float*)d_in[0];
    const float* mem = (const float*)d_in[1];
    const float* Wq  = (const float*)d_in[2];
    const float* Wk  = (const float*)d_in[3];
    const float* Wv  = (const float*)d_in[4];
    const float* Wo  = (const float*)d_in[5];

    constexpr int  B = 4, L = 2048, D = 1024;
    constexpr long LD = (long)L * D;
    constexpr long LL = (long)L * L;
    constexpr size_t CH = 1u << 24;

    char* ws = (char*)d_ws;
    bf* Q   = (bf*)(ws + 0 * CH);
    bf* Kp  = (bf*)(ws + 1 * CH);
    bf* Vt  = (bf*)(ws + 2 * CH);
    bf* Wb  = (bf*)(ws + 3 * CH);
    bf* Wqb = Wb;
    bf* Wkb = Wb + (long)(1 << 20);
    bf* Wvb = Wb + (long)2 * (1 << 20);
    bf* Wob = Wb + (long)3 * (1 << 20);
    bf* AO  = Q;

    bf* xb   = (bf*)d_out;
    bf* memb = (bf*)d_out + B * LD;
    bf* Lg   = (bf*)d_out;

    const float qscale = 0.03125f;

    cvt2<<<dim3(1024, 1, 2), dim3(256), 0, stream>>>(x, mem, xb, memb, B * LD);
    cvt_w<<<dim3(512, 1, 4), dim3(256), 0, stream>>>(Wq, Wk, Wv, Wo, Wb);

    // 3. Q = x@Wq^T * s, K = mem@Wk^T : M=8192, N=1024, K=1024 (256x256 tiles)
    gemm256_qk<<<dim3(4, 32, 2), dim3(512), 0, stream>>>(
        xb, memb, Wqb, Wkb, Q, Kp, qscale);

    // 4. Vt[b] = Wvb (.) memb[b]^T : M=1024, N=2048, K=1024 (128x256 tiles)
    gemm128<bf><<<dim3(8, 8, 4), dim3(512), 0, stream>>>(
        Wvb, memb, Vt, D, L, 0, LD, (long)D * L, 1.f);

    // 5. logits[b][q,m] = Q[b][q,:].Kp[b][m,:] : M=N=2048, K=1024 (256x256)
    gemm256<bf><<<dim3(8, 8, 4), dim3(512), 0, stream>>>(
        Q, Kp, Lg, D, L, LD, LD, LL, 1.f);

    // 6. softmax in place
    softmax_rows_2048<<<dim3(B * L), dim3(256), 0, stream>>>(Lg);

    // 7. AO[b][q,e] = P[b][q,:].Vt[b][e,:] : M=2048, N=1024, K=2048 (128x256)
    gemm128<bf><<<dim3(4, 16, 4), dim3(512), 0, stream>>>(
        Lg, Vt, AO, L, D, LL, (long)D * L, LD, 1.f);

    // 8. out = AO @ Wob^T : M=8192, N=1024, K=1024 (128x256)
    gemm128<float><<<dim3(4, 64, 1), dim3(512), 0, stream>>>(
        AO, Wob, (float*)d_out, D, D, 0, 0, 0, 1.f);
}

// Round 7
// 294.277 us; speedup vs baseline: 1.0073x; 1.0073x over previous
//
#include <hip/hip_runtime.h>
#include <hip/hip_bf16.h>

typedef unsigned short u16;
typedef __bf16 bf16x8 __attribute__((ext_vector_type(8)));
typedef float floatx4 __attribute__((ext_vector_type(4)));
typedef __hip_bfloat16 bf;

__device__ __forceinline__ __bf16 f2b(float f) {
    __hip_bfloat16 h = __float2bfloat16(f);
    return *reinterpret_cast<__bf16*>(&h);
}
__device__ __forceinline__ bf16x8 ld8f(const float* p) {
    float4 a = ((const float4*)p)[0];
    float4 b = ((const float4*)p)[1];
    bf16x8 r;
    r[0] = f2b(a.x); r[1] = f2b(a.y); r[2] = f2b(a.z); r[3] = f2b(a.w);
    r[4] = f2b(b.x); r[5] = f2b(b.y); r[6] = f2b(b.z); r[7] = f2b(b.w);
    return r;
}
__device__ __forceinline__ void storev(float* p, float v) { *p = v; }
__device__ __forceinline__ void storev(bf* p, float v)    { *p = __float2bfloat16(v); }

// async 16-B global->LDS (dest = wave-uniform base + lane*16)
__device__ __forceinline__ void gl16(const bf* g, u16* l) {
    __builtin_amdgcn_global_load_lds(
        (const __attribute__((address_space(1))) void*)g,
        (__attribute__((address_space(3))) void*)l, 16, 0, 0);
}

// T1 bijective XCD swizzle (all grids have nwg % 8 == 0)
__device__ __forceinline__ void swz3(int& bx, int& by, int& bz) {
    const int nx = gridDim.x, ny = gridDim.y, nz = gridDim.z;
    const int lid = blockIdx.x + nx * (blockIdx.y + ny * blockIdx.z);
    const int cpx = (nx * ny * nz) >> 3;
    const int s = (lid & 7) * cpx + (lid >> 3);
    bx = s % nx;
    const int r = s / nx;
    by = r % ny;
    bz = r / ny;
}

#define FENCE asm volatile("" ::: "memory")
#define BARx  __builtin_amdgcn_s_barrier()
#define LGKM0 asm volatile("s_waitcnt lgkmcnt(0)" ::: "memory")
#define VM3   asm volatile("s_waitcnt vmcnt(3)" ::: "memory")
#define VM0   asm volatile("s_waitcnt vmcnt(0)" ::: "memory")
#define SP1   __builtin_amdgcn_s_setprio(1)
#define SP0   __builtin_amdgcn_s_setprio(0)

// ============================================================================
// R7: SKEWED 128x256 4-phase NT GEMM.  C[m,n] = scale * sum_k A[m,k]*B[n,k].
//
// R2-R6 post-mortem: MfmaUtil pinned at 25-28% across 5 structural variants
// because every variant had phase-p MFMA consume phase-p ds_reads: all 8
// waves' reads interleave in the CU-shared LDS FIFO, so every wave's wait
// clears only near the end of the ~600-cyc queue drain, serializing
// {drain | MFMA} at CU level (1800 cyc/phase ~= 600 + 621 + slack; 621/1800
// = measured MfmaUtil).  Fix: DATAFLOW SKEW — phase p reads into register
// set for phase p+1's MFMA; MFMA(p) runs on the completed set from p-1 with
// no wait; the end-of-phase LGKM0 (required anyway so next-phase staging
// can't race in-flight reads) is covered by the MFMA window.
//
// Geometry/staging/VM3/read-phases IDENTICAL to the R5/R6 refcheck'd core:
// BK=64, 512 thr, 8 waves 2Mx4N, wave-out 64x64, LDS 96 KiB, k-swizzle
// (SQ_LDS_BANK_CONFLICT = 0 measured).  Only MFMA timing moved one phase
// later, so the staging staircase / drain proofs carry over; the per-phase
// LGKM0 additionally guarantees every read is serviced inside its phase,
// before the barrier that precedes any staging of that region.
//
// Phase map (iteration = K-tiles t=2it, t+1; buf0 holds t, buf1 holds t+1):
//   ph1: RD {aX,b0X}<-buf0 | stage buf1.B(t+1)[skip it=0] | M4' = (aY,b1Y)
//   ph2: RD {b1X}   <-buf0 | stage buf0.{A,B0u0}(t+2)     | M1 = (aX,b0X); VM3
//   ph3: RD {aY,b0Y}<-buf1 | stage buf0.{B rest}(t+2)     | M2 = (aX,b1X)
//   ph4: RD {b1Y}   <-buf1 | stage buf1.{A,B0u0}(t+3)     | M3 = (aY,b0Y); VM3
// Epilogue: M4 = (aY,b1Y) of tile T-1.   Requires K % 128 == 0.
// ============================================================================

#define ST_A(h, kt, Ab) \
    gl16(Asrc + (long)((h) * 32) * K + (long)(kt) * 64, (Ab) + (h) * 4096 + tid * 8)
#define ST_Bu0(c, kt, Bb) \
    gl16(Bsrc + (long)((c) * 32) * K + (long)(kt) * 64, (Bb) + (c) * 8192 + tid * 8)
#define ST_Bu1(c, kt, Bb) \
    gl16(Bsrc + (long)((c) * 32 + 128) * K + (long)(kt) * 64, (Bb) + (c) * 8192 + 4096 + tid * 8)

#define RD_A(dst, h, Ab) do { _Pragma("unroll") \
    for (int q_ = 0; q_ < 2; q_++) { \
        const u16* p_ = (Ab) + ((h) * 64 + wg * 32 + q_ * 16 + fr) * 64; \
        dst[q_ * 2 + 0] = *(const bf16x8*)(p_ + kl0); \
        dst[q_ * 2 + 1] = *(const bf16x8*)(p_ + kl1); \
    } } while (0)

#define RD_B(dst, c, Bb) do { _Pragma("unroll") \
    for (int j_ = 0; j_ < 2; j_++) { \
        const u16* p_ = (Bb) + ((c) * 128 + w4 * 32 + j_ * 16 + fr) * 64; \
        dst[j_ * 2 + 0] = *(const bf16x8*)(p_ + kl0); \
        dst[j_ * 2 + 1] = *(const bf16x8*)(p_ + kl1); \
    } } while (0)

// M-block: both h quadrants against one b-set (c = which B half for acc idx)
#define MBLK(c, a0v, a1v, bv) do { _Pragma("unroll") \
    for (int q_ = 0; q_ < 2; q_++) _Pragma("unroll") \
    for (int j_ = 0; j_ < 2; j_++) _Pragma("unroll") \
    for (int kk_ = 0; kk_ < 2; kk_++) { \
        acc[q_][(c) * 2 + j_] = __builtin_amdgcn_mfma_f32_16x16x32_bf16( \
            a0v[q_ * 2 + kk_], bv[j_ * 2 + kk_], acc[q_][(c) * 2 + j_], 0, 0, 0); \
        acc[2 + q_][(c) * 2 + j_] = __builtin_amdgcn_mfma_f32_16x16x32_bf16( \
            a1v[q_ * 2 + kk_], bv[j_ * 2 + kk_], acc[2 + q_][(c) * 2 + j_], 0, 0, 0); \
    } } while (0)

template <typename OutT>
__device__ __forceinline__ void gemm128_core(
    const bf* __restrict__ A, const bf* __restrict__ B, OutT* __restrict__ C,
    int K, int N, int m_blk, int n_blk, float scale, u16* lds)
{
    const int tid  = threadIdx.x;
    const int w    = tid >> 6, lane = tid & 63;
    const int wg   = w >> 2, w4 = w & 3;
    const int fr   = lane & 15, kg = lane >> 4;

    u16* const A0b = lds;
    u16* const B0b = lds + 8192;
    u16* const A1b = lds + 24576;
    u16* const B1b = lds + 32768;

    const int kl0 = (kg * 8) ^ ((fr & 7) << 3);
    const int kl1 = kl0 ^ 32;

    const int sr  = tid >> 3;
    const int scs = ((tid & 7) * 8) ^ ((sr & 7) << 3);
    const bf* Asrc = A + (long)(m_blk + (tid >> 8) * 64 + (sr & 31)) * K + scs;
    const bf* Bsrc = B + (long)(n_blk + (tid >> 8) * 64 + (sr & 31)) * K + scs;

    floatx4 acc[4][4];
#pragma unroll
    for (int i = 0; i < 4; i++)
#pragma unroll
        for (int j = 0; j < 4; j++) acc[i][j] = (floatx4){0.f, 0.f, 0.f, 0.f};

    // two operand register sets (X: tile t, Y: tile t+1) — all static names
    bf16x8 aX0[4], aX1[4], aY0[4], aY1[4];
    bf16x8 b0X[4], b1X[4], b0Y[4], b1Y[4];

    const int T     = K >> 6;
    const int iters = T >> 1;

    // prologue: stage tiles 0 -> buf0, 1 -> buf1 fully; drain
    ST_A(0, 0, A0b); ST_A(1, 0, A0b);
    ST_Bu0(0, 0, B0b); ST_Bu1(0, 0, B0b); ST_Bu0(1, 0, B0b); ST_Bu1(1, 0, B0b);
    ST_A(0, 1, A1b); ST_A(1, 1, A1b);
    ST_Bu0(0, 1, B1b); ST_Bu1(0, 1, B1b); ST_Bu0(1, 1, B1b); ST_Bu1(1, 1, B1b);
    VM0; BARx; FENCE;

    for (int it = 0; it < iters; ++it) {
        const int t   = it * 2;
        const int ts0 = (t + 2 < T) ? t + 2 : 0;   // clamped: garbage unused
        const int ts1 = (t + 3 < T) ? t + 3 : 0;

        // ph1: read {aX,b0X} from buf0(t); M4' = (aY,b1Y) of tile t-1
        RD_A(aX0, 0, A0b); RD_A(aX1, 1, A0b); RD_B(b0X, 0, B0b);
        if (it) {
            ST_Bu1(0, t + 1, B1b); ST_Bu0(1, t + 1, B1b); ST_Bu1(1, t + 1, B1b);
            SP1; MBLK(1, aY0, aY1, b1Y); SP0;
        }
        LGKM0; BARx; FENCE;

        // ph2: read {b1X}; M1 = (aX,b0X); VM3 drains buf1 tile t+1
        RD_B(b1X, 1, B0b);
        ST_A(0, ts0, A0b); ST_A(1, ts0, A0b); ST_Bu0(0, ts0, B0b);
        SP1; MBLK(0, aX0, aX1, b0X); SP0;
        LGKM0; VM3; BARx; FENCE;

        // ph3: read {aY,b0Y} from buf1(t+1); M2 = (aX,b1X)
        RD_A(aY0, 0, A1b); RD_A(aY1, 1, A1b); RD_B(b0Y, 0, B1b);
        ST_Bu1(0, ts0, B0b); ST_Bu0(1, ts0, B0b); ST_Bu1(1, ts0, B0b);
        SP1; MBLK(1, aX0, aX1, b1X); SP0;
        LGKM0; BARx; FENCE;

        // ph4: read {b1Y}; M3 = (aY,b0Y); VM3 drains buf0 tile t+2
        RD_B(b1Y, 1, B1b);
        ST_A(0, ts1, A1b); ST_A(1, ts1, A1b); ST_Bu0(0, ts1, B1b);
        SP1; MBLK(0, aY0, aY1, b0Y); SP0;
        LGKM0; VM3; BARx; FENCE;
    }
    // epilogue: last quadrant pair of tile T-1
    MBLK(1, aY0, aY1, b1Y);

    // C-write: col=lane&15, row=(lane>>4)*4+reg  [m89/m91]
    const long c_col0 = n_blk + w4 * 64 + fr;
    const long c_row0 = m_blk + wg * 64 + (lane >> 4) * 4;
#pragma unroll
    for (int rf = 0; rf < 4; rf++)
#pragma unroll
        for (int r = 0; r < 4; r++) {
            const long row = c_row0 + rf * 16 + r;
#pragma unroll
            for (int cf = 0; cf < 4; cf++)
                storev(&C[row * N + c_col0 + cf * 16], acc[rf][cf][r] * scale);
        }
}

template <typename OutT>
__global__ __launch_bounds__(512)
void gemm128(const bf* __restrict__ A, const bf* __restrict__ B,
             OutT* __restrict__ C, int K, int N,
             long sA, long sB, long sC, float scale)
{
    __shared__ __align__(16) u16 lds[49152];   // 96 KiB
    int bx, by, bz; swz3(bx, by, bz);
    gemm128_core(A + bz * sA, B + bz * sB, C + bz * sC,
                 K, N, by * 128, bx * 256, scale, lds);
}

__global__ __launch_bounds__(512)
void gemm128_qk(const bf* __restrict__ xb, const bf* __restrict__ memb,
                const bf* __restrict__ Wqb, const bf* __restrict__ Wkb,
                bf* __restrict__ Q, bf* __restrict__ Kp, float qscale)
{
    __shared__ __align__(16) u16 lds[49152];
    int bx, by, bz; swz3(bx, by, bz);
    gemm128_core(bz ? memb : xb, bz ? Wkb : Wqb, bz ? Kp : Q, 1024, 1024,
                 by * 128, bx * 256, bz ? 1.f : qscale, lds);
}

// ============================================================================
// fp32 -> bf16 conversion pre-pass
// ============================================================================
__global__ __launch_bounds__(256)
void cvt2(const float* __restrict__ a, const float* __restrict__ b,
          bf* __restrict__ da, bf* __restrict__ db, long n)
{
    const float* s = blockIdx.z ? b : a;
    bf* d = blockIdx.z ? db : da;
    const long stride = (long)gridDim.x * 256;
    for (long i = (long)blockIdx.x * 256 + threadIdx.x; i * 8 < n; i += stride)
        *(bf16x8*)(d + i * 8) = ld8f(s + i * 8);
}

__global__ __launch_bounds__(256)
void cvt_w(const float* __restrict__ w0, const float* __restrict__ w1,
           const float* __restrict__ w2, const float* __restrict__ w3,
           bf* __restrict__ d)
{
    const int z = blockIdx.z;
    const float* s = (z == 0) ? w0 : (z == 1) ? w1 : (z == 2) ? w2 : w3;
    bf* dz = d + (long)z * (1 << 20);
    const long i = ((long)blockIdx.x * 256 + threadIdx.x) * 8;
    *(bf16x8*)(dz + i) = ld8f(s + i);
}

// ============================================================================
// In-place bf16 row softmax over 2048 logits; one block per row.
// ============================================================================
__global__ __launch_bounds__(256)
void softmax_rows_2048(bf* __restrict__ X)
{
    const long row = blockIdx.x;
    const int t = threadIdx.x;
    const int wave = t >> 6, lane = t & 63;
    __shared__ float red[8];

    float v[8];
    float m = -1e30f;
#pragma unroll
    for (int i = 0; i < 8; i++) {
        v[i] = __bfloat162float(X[row * 2048 + t + i * 256]);
        m = fmaxf(m, v[i]);
    }
#pragma unroll
    for (int o = 32; o > 0; o >>= 1) m = fmaxf(m, __shfl_xor(m, o, 64));
    if (lane == 0) red[wave] = m;
    __syncthreads();
    m = fmaxf(fmaxf(red[0], red[1]), fmaxf(red[2], red[3]));

    float s = 0.f;
#pragma unroll
    for (int i = 0; i < 8; i++) { v[i] = __expf(v[i] - m); s += v[i]; }
#pragma unroll
    for (int o = 32; o > 0; o >>= 1) s += __shfl_xor(s, o, 64);
    if (lane == 0) red[4 + wave] = s;
    __syncthreads();
    s = red[4] + red[5] + red[6] + red[7];

    const float inv = 1.f / s;
#pragma unroll
    for (int i = 0; i < 8; i++)
        X[row * 2048 + t + i * 256] = __float2bfloat16(v[i] * inv);
}

// ============================================================================
// Pipeline (8 dispatches), all GEMMs on the skewed 128x256 core:
//   1. cvt2   x,mem -> xb,memb bf16 (in d_out, dead after logits)
//   2. cvt_w  weights -> bf16 (ws chunk 3)
//   3. qk     grid(4,64,2)=512     M=8192,N=1024,K=1024
//   4. Vt     grid(8,8,4)=256      M=1024,N=2048,K=1024
//   5. logits grid(8,16,4)=512     M=N=2048,K=1024 -> Lg in d_out
//   6. softmax 8192 blk in place
//   7. AO     grid(4,16,4)=256     M=2048,N=1024,K=2048 (aliases Q)
//   8. final  grid(4,64,1)=256     M=8192,N=1024,K=1024 -> out fp32
// Workspace: Q/AO 16 + Kp 16 + Vt 16 + Wb 8 = 56 MiB.
// ============================================================================
extern "C" void kernel_launch(void* const* d_in, const int* in_sizes, int n_in,
                              void* d_out, int out_size, void* d_ws, size_t ws_size,
                              hipStream_t stream)
{
    const float* x   = (const float*)d_in[0];
    const float* mem = (const float*)d_in[1];
    const float* Wq  = (const float*)d_in[2];
    const float* Wk  = (const float*)d_in[3];
    const float* Wv  = (const float*)d_in[4];
    const float* Wo  = (const float*)d_in[5];

    constexpr int  B = 4, L = 2048, D = 1024;
    constexpr long LD = (long)L * D;
    constexpr long LL = (long)L * L;
    constexpr size_t CH = 1u << 24;

    char* ws = (char*)d_ws;
    bf* Q   = (bf*)(ws + 0 * CH);
    bf* Kp  = (bf*)(ws + 1 * CH);
    bf* Vt  = (bf*)(ws + 2 * CH);
    bf* Wb  = (bf*)(ws + 3 * CH);
    bf* Wqb = Wb;
    bf* Wkb = Wb + (long)(1 << 20);
    bf* Wvb = Wb + (long)2 * (1 << 20);
    bf* Wob = Wb + (long)3 * (1 << 20);
    bf* AO  = Q;

    bf* xb   = (bf*)d_out;
    bf* memb = (bf*)d_out + B * LD;
    bf* Lg   = (bf*)d_out;

    const float qscale = 0.03125f;

    cvt2<<<dim3(1024, 1, 2), dim3(256), 0, stream>>>(x, mem, xb, memb, B * LD);
    cvt_w<<<dim3(512, 1, 4), dim3(256), 0, stream>>>(Wq, Wk, Wv, Wo, Wb);

    // 3. Q = x@Wq^T * s, K = mem@Wk^T
    gemm128_qk<<<dim3(4, 64, 2), dim3(512), 0, stream>>>(
        xb, memb, Wqb, Wkb, Q, Kp, qscale);

    // 4. Vt[b] = Wvb (.) memb[b]^T : M=1024, N=2048, K=1024
    gemm128<bf><<<dim3(8, 8, 4), dim3(512), 0, stream>>>(
        Wvb, memb, Vt, D, L, 0, LD, (long)D * L, 1.f);

    // 5. logits[b][q,m] = Q[b][q,:].Kp[b][m,:] : M=N=2048, K=1024
    gemm128<bf><<<dim3(8, 16, 4), dim3(512), 0, stream>>>(
        Q, Kp, Lg, D, L, LD, LD, LL, 1.f);

    // 6. softmax in place
    softmax_rows_2048<<<dim3(B * L), dim3(256), 0, stream>>>(Lg);

    // 7. AO[b][q,e] = P[b][q,:].Vt[b][e,:] : M=2048, N=1024, K=2048
    gemm128<bf><<<dim3(4, 16, 4), dim3(512), 0, stream>>>(
        Lg, Vt, AO, L, D, LL, (long)D * L, LD, 1.f);

    // 8. out = AO @ Wob^T : M=8192, N=1024, K=1024
    gemm128<float><<<dim3(4, 64, 1), dim3(512), 0, stream>>>(
        AO, Wob, (float*)d_out, D, D, 0, 0, 0, 1.f);
}